// Round 3
// baseline (541.107 us; speedup 1.0000x reference)
//
#include <hip/hip_runtime.h>
#include <math.h>

// ---------------------------------------------------------------------------
// CapsNet forward, fully fused routing (block = sample), pred never built:
//   s  = W_o . y  + bias_o * sum(c)     with y = sum_i c_i h[:,i]
//   db = u . h    + v.bias_o            with u = v . W_o
// Round-3 changes: W register-batching (VGPR cap 128), 3 barriers/iter,
// BL/bias prefetch, float4 c-reads in y-phase.
// ---------------------------------------------------------------------------

__global__ __launch_bounds__(256) void conv_squash_kernel(
    const float* __restrict__ x,   // [128,64,8,8]
    const float* __restrict__ Wb,  // [64,64,3,3]
    const float* __restrict__ bb,  // [64]
    float* __restrict__ h)         // [128,64,64]
{
    __shared__ float xs[6400];
    __shared__ float hs[4096];
    __shared__ float scl[64];
    const int b = blockIdx.x;
    const int t = threadIdx.x;

    for (int idx = t; idx < 6400; idx += 256) xs[idx] = 0.f;
    __syncthreads();
    #pragma unroll
    for (int k = 0; k < 4; ++k) {
        int idx4 = t + k * 256;
        float4 v = *(const float4*)&x[(size_t)b * 4096 + idx4 * 4];
        int e0 = idx4 * 4;
        int c  = e0 >> 6;
        int hw = e0 & 63;
        int r = hw >> 3, cc = hw & 7;
        float* xp = &xs[c * 100 + (r + 1) * 10 + (cc + 1)];
        xp[0] = v.x; xp[1] = v.y; xp[2] = v.z; xp[3] = v.w;
    }
    __syncthreads();

    const int oc = t >> 2;
    const int hg = t & 3;
    float acc[16];
    #pragma unroll
    for (int k = 0; k < 16; ++k) acc[k] = 0.f;

    const float* wp = Wb + (size_t)oc * 64 * 9;
    for (int ic = 0; ic < 64; ++ic) {
        float w[9];
        #pragma unroll
        for (int j = 0; j < 9; ++j) w[j] = wp[ic * 9 + j];
        const float* xr = &xs[ic * 100];
        #pragma unroll
        for (int k = 0; k < 16; ++k) {
            int hw = hg * 16 + k;
            int r = hw >> 3, cc = hw & 7;
            int p0 = r * 10 + cc;
            float a = acc[k];
            a = fmaf(w[0], xr[p0],      a);
            a = fmaf(w[1], xr[p0 + 1],  a);
            a = fmaf(w[2], xr[p0 + 2],  a);
            a = fmaf(w[3], xr[p0 + 10], a);
            a = fmaf(w[4], xr[p0 + 11], a);
            a = fmaf(w[5], xr[p0 + 12], a);
            a = fmaf(w[6], xr[p0 + 20], a);
            a = fmaf(w[7], xr[p0 + 21], a);
            a = fmaf(w[8], xr[p0 + 22], a);
            acc[k] = a;
        }
    }
    float bias = bb[oc];
    #pragma unroll
    for (int k = 0; k < 16; ++k) {
        float v = acc[k] + bias;
        v = v > 0.f ? v : 0.f;
        hs[oc * 64 + hg * 16 + k] = v;
    }
    __syncthreads();
    if (t < 64) {
        float n2 = 0.f;
        for (int c = 0; c < 64; ++c) { float v = hs[c * 64 + t]; n2 = fmaf(v, v, n2); }
        scl[t] = (n2 / (1.f + n2)) * rsqrtf(n2 + 1e-8f);
    }
    __syncthreads();
    #pragma unroll
    for (int k = 0; k < 4; ++k) {
        int idx4 = t + k * 256;
        int e0 = idx4 * 4;
        int hw0 = e0 & 63;
        float4 o;
        o.x = hs[e0 + 0] * scl[hw0 + 0];
        o.y = hs[e0 + 1] * scl[hw0 + 1];
        o.z = hs[e0 + 2] * scl[hw0 + 2];
        o.w = hs[e0 + 3] * scl[hw0 + 3];
        *(float4*)&h[(size_t)b * 4096 + e0] = o;
    }
}

__global__ __launch_bounds__(1024, 4) void caps_fused(
    const float* __restrict__ h0,
    const float* __restrict__ W1, const float* __restrict__ b1,
    const float* __restrict__ W2, const float* __restrict__ b2,
    const float* __restrict__ b_basic, const float* __restrict__ b_cls,
    float* __restrict__ out)
{
    __shared__ float HTa[4096];
    __shared__ float HTb[4096];
    __shared__ float BL[4096];
    __shared__ float CC[4096];

    const int b    = blockIdx.x;
    const int t    = threadIdx.x;
    const int wv   = t >> 6;      // wave 0..15
    const int lane = t & 63;
    const int Q    = lane & 15;
    const int G    = lane >> 4;

    // initial transposed load: HTa[i][c] = h0[b][c][i]
    {
        float4 v = *(const float4*)&h0[(size_t)b * 4096 + t * 4];
        int c  = t >> 4;
        int i0 = (t & 15) * 4;
        HTa[(i0 + 0) * 64 + c] = v.x;
        HTa[(i0 + 1) * 64 + c] = v.y;
        HTa[(i0 + 2) * 64 + c] = v.z;
        HTa[(i0 + 3) * 64 + c] = v.w;
    }

    for (int L = 0; L < 4; ++L) {
        const bool fin = (L == 3);
        const int O = fin ? 10 : 64;
        const float* W    = fin ? W2 : W1;
        const float* bias = fin ? b2 : b1;
        float* HT  = (L & 1) ? HTb : HTa;
        float* HTn = (L & 1) ? HTa : HTb;
        float* PP  = HTn;          // [16][64] overlay (rows 0..15 dead here)

        // prefetch this layer's logits into regs (hides under prev-layer tail)
        float4 blv = make_float4(0.f, 0.f, 0.f, 0.f);
        if (fin) {
            if (t < 160) blv = *(const float4*)&b_cls[(size_t)b * 640 + t * 4];
        } else {
            blv = *(const float4*)&b_basic[(((size_t)L * 128 + b) << 12) + t * 4];
        }
        __syncthreads();           // layer top: HT (=prev HTn) ready, BL dead
        if (!fin || t < 160) *(float4*)&BL[t * 4] = blv;

        for (int it = 0; it < 3; ++it) {
            __syncthreads();   // A: BL current (init or db), HTn v-rows dead
            // -- softmax pass 1: exp + per-wave partial sums --
            float part = 0.f;
            #pragma unroll
            for (int r = 0; r < 4; ++r) {
                int o = 4 * wv + r;
                if (o < O) {
                    float e = expf(BL[o * 64 + lane]);
                    CC[o * 64 + lane] = e;
                    part += e;
                }
            }
            PP[wv * 64 + lane] = part;
            __syncthreads();   // B
            // every wave computes the denominator, scales its OWN rows
            {
                float den = 0.f;
                #pragma unroll
                for (int w2 = 0; w2 < 16; ++w2) den += PP[w2 * 64 + lane];
                float rden = 1.f / den;
                #pragma unroll
                for (int r = 0; r < 4; ++r) {
                    int o = 4 * wv + r;
                    if (o < O) CC[o * 64 + lane] *= rden;
                }
            }
            __syncthreads();   // C: c complete; HT stable from here on

            // prefetch the 4 bias values (global) early
            float bb4[4];
            #pragma unroll
            for (int oo = 0; oo < 4; ++oo) {
                int o = wv + 16 * oo;
                bb4[oo] = (o < O) ? bias[o * 64 + lane] : 0.f;
            }

            // -- Y: y[o,c] = sum_i c[o,i] h[c,i]; 4 o's per wave, i k-split --
            float yy[4][4];
            float sc[4];
            #pragma unroll
            for (int a = 0; a < 4; ++a) {
                sc[a] = 0.f;
                #pragma unroll
                for (int j2 = 0; j2 < 4; ++j2) yy[a][j2] = 0.f;
            }
            if (wv < O) {
                #pragma unroll
                for (int j = 0; j < 4; ++j) {
                    float4 h4[4];
                    #pragma unroll
                    for (int r = 0; r < 4; ++r)
                        h4[r] = *(float4*)&HT[(G * 16 + 4 * j + r) * 64 + 4 * Q];
                    #pragma unroll
                    for (int oo = 0; oo < 4; ++oo) {
                        int o = wv + 16 * oo;
                        if (o < O) {
                            float4 c4 = *(const float4*)&CC[o * 64 + G * 16 + 4 * j];
                            yy[oo][0] = fmaf(c4.x, h4[0].x, yy[oo][0]);
                            yy[oo][1] = fmaf(c4.x, h4[0].y, yy[oo][1]);
                            yy[oo][2] = fmaf(c4.x, h4[0].z, yy[oo][2]);
                            yy[oo][3] = fmaf(c4.x, h4[0].w, yy[oo][3]);
                            yy[oo][0] = fmaf(c4.y, h4[1].x, yy[oo][0]);
                            yy[oo][1] = fmaf(c4.y, h4[1].y, yy[oo][1]);
                            yy[oo][2] = fmaf(c4.y, h4[1].z, yy[oo][2]);
                            yy[oo][3] = fmaf(c4.y, h4[1].w, yy[oo][3]);
                            yy[oo][0] = fmaf(c4.z, h4[2].x, yy[oo][0]);
                            yy[oo][1] = fmaf(c4.z, h4[2].y, yy[oo][1]);
                            yy[oo][2] = fmaf(c4.z, h4[2].z, yy[oo][2]);
                            yy[oo][3] = fmaf(c4.z, h4[2].w, yy[oo][3]);
                            yy[oo][0] = fmaf(c4.w, h4[3].x, yy[oo][0]);
                            yy[oo][1] = fmaf(c4.w, h4[3].y, yy[oo][1]);
                            yy[oo][2] = fmaf(c4.w, h4[3].z, yy[oo][2]);
                            yy[oo][3] = fmaf(c4.w, h4[3].w, yy[oo][3]);
                            sc[oo] += (c4.x + c4.y) + (c4.z + c4.w);
                        }
                    }
                }
                #pragma unroll
                for (int m = 16; m <= 32; m <<= 1) {
                    #pragma unroll
                    for (int oo = 0; oo < 4; ++oo) {
                        yy[oo][0] += __shfl_xor(yy[oo][0], m, 64);
                        yy[oo][1] += __shfl_xor(yy[oo][1], m, 64);
                        yy[oo][2] += __shfl_xor(yy[oo][2], m, 64);
                        yy[oo][3] += __shfl_xor(yy[oo][3], m, 64);
                        sc[oo]    += __shfl_xor(sc[oo],    m, 64);
                    }
                }
                if (G == 0) {
                    #pragma unroll
                    for (int oo = 0; oo < 4; ++oo) {
                        int o = wv + 16 * oo;
                        if (o < O) {
                            float4 w4;
                            w4.x = yy[oo][0]; w4.y = yy[oo][1];
                            w4.z = yy[oo][2]; w4.w = yy[oo][3];
                            *(float4*)&CC[o * 64 + 4 * Q] = w4;   // y row
                        }
                    }
                }
            }

            // -- per-o: s = W_o.y + bias*sumc, squash, u = v.W_o, db --
            #pragma unroll 1
            for (int oo = 0; oo < 4; ++oo) {
                const int o = wv + 16 * oo;
                if (o >= O) break;
                const float* Wo = W + ((size_t)(o * 64 + lane) << 6);
                // batch-load the full W row (16 float4 = 64 VGPR)
                float4 ws[16];
                #pragma unroll
                for (int k = 0; k < 16; ++k) ws[k] = *(const float4*)&Wo[4 * k];
                float p0 = 0.f, p1 = 0.f, p2 = 0.f, p3 = 0.f;
                #pragma unroll
                for (int k = 0; k < 16; ++k) {
                    float4 y4 = *(const float4*)&CC[o * 64 + 4 * k];
                    p0 = fmaf(ws[k].x, y4.x, p0);
                    p1 = fmaf(ws[k].y, y4.y, p1);
                    p2 = fmaf(ws[k].z, y4.z, p2);
                    p3 = fmaf(ws[k].w, y4.w, p3);
                }
                float s = (p0 + p1) + (p2 + p3);
                s = fmaf(bb4[oo], sc[oo], s);

                float n2 = s * s;
                #pragma unroll
                for (int m = 1; m < 64; m <<= 1) n2 += __shfl_xor(n2, m, 64);
                float v = s * (n2 / (1.f + n2)) * rsqrtf(n2 + 1e-8f);
                HTn[o * 64 + lane] = v;                 // v row = next HT
                if (fin && it == 2) out[((size_t)b * 10 + o) * 64 + lane] = v;

                if (it < 2) {
                    float vd = v * bb4[oo];
                    #pragma unroll
                    for (int m = 1; m < 64; m <<= 1) vd += __shfl_xor(vd, m, 64);
                    // u-phase: batch-load W slice (rows G*16+k, cols 4Q..)
                    float4 wu[16];
                    #pragma unroll
                    for (int k = 0; k < 16; ++k)
                        wu[k] = *(const float4*)&W[((size_t)(o * 64 + G * 16 + k) << 6) + 4 * Q];
                    float ux = 0.f, uy = 0.f, uz = 0.f, uw = 0.f;
                    #pragma unroll
                    for (int k = 0; k < 16; ++k) {
                        float vv = HTn[o * 64 + G * 16 + k];
                        ux = fmaf(vv, wu[k].x, ux);
                        uy = fmaf(vv, wu[k].y, uy);
                        uz = fmaf(vv, wu[k].z, uz);
                        uw = fmaf(vv, wu[k].w, uw);
                    }
                    #pragma unroll
                    for (int m = 16; m <= 32; m <<= 1) {
                        ux += __shfl_xor(ux, m, 64);
                        uy += __shfl_xor(uy, m, 64);
                        uz += __shfl_xor(uz, m, 64);
                        uw += __shfl_xor(uw, m, 64);
                    }
                    if (G == 0) {
                        float4 uu; uu.x = ux; uu.y = uy; uu.z = uz; uu.w = uw;
                        *(float4*)&CC[o * 64 + 4 * Q] = uu;   // u row
                    }
                    // db[o,i=lane] = sum_c u[c] h[c,i]; XOR quad rotation
                    float acc2 = 0.f;
                    #pragma unroll
                    for (int k = 0; k < 16; ++k) {
                        int cq = k ^ Q;
                        float4 uu = *(float4*)&CC[o * 64 + 4 * cq];
                        float4 hh = *(float4*)&HT[lane * 64 + 4 * cq];
                        acc2 = fmaf(uu.x, hh.x, acc2);
                        acc2 = fmaf(uu.y, hh.y, acc2);
                        acc2 = fmaf(uu.z, hh.z, acc2);
                        acc2 = fmaf(uu.w, hh.w, acc2);
                    }
                    BL[o * 64 + lane] += acc2 + vd;
                }
            }
        }
    }
}

extern "C" void kernel_launch(void* const* d_in, const int* in_sizes, int n_in,
                              void* d_out, int out_size, void* d_ws, size_t ws_size,
                              hipStream_t stream) {
    const float* x       = (const float*)d_in[0];
    const float* Wb      = (const float*)d_in[1];
    const float* bb      = (const float*)d_in[2];
    const float* W1      = (const float*)d_in[3];
    const float* b1      = (const float*)d_in[4];
    const float* W2      = (const float*)d_in[5];
    const float* b2      = (const float*)d_in[6];
    const float* b_basic = (const float*)d_in[7];
    const float* b_cls   = (const float*)d_in[8];
    float* out = (float*)d_out;

    float* h0 = (float*)d_ws;   // [128,64,64]

    conv_squash_kernel<<<128, 256, 0, stream>>>(x, Wb, bb, h0);
    caps_fused<<<128, 1024, 0, stream>>>(h0, W1, b1, W2, b2, b_basic, b_cls, out);
}

// Round 4
// 437.390 us; speedup vs baseline: 1.2371x; 1.2371x over previous
//
#include <hip/hip_runtime.h>
#include <math.h>
#include <type_traits>

// ---------------------------------------------------------------------------
// CapsNet forward, fully fused routing (block = sample), pred never built:
//   s  = W_o . y  + bias_o * sum(c)     with y = sum_i c_i h[:,i]
//   db = u . h    + v.bias_o            with u = v . W_o
// Round-4: k-outer / o-inner interleaving of the W-load dot products (4
// independent load streams, no named register buffers -> no spills),
// layer-hoisted bias/pointers, fused (n2, s.bias) butterfly, templated
// final-layer specialization.
// ---------------------------------------------------------------------------

__global__ __launch_bounds__(256) void conv_squash_kernel(
    const float* __restrict__ x,   // [128,64,8,8]
    const float* __restrict__ Wb,  // [64,64,3,3]
    const float* __restrict__ bb,  // [64]
    float* __restrict__ h)         // [128,64,64]
{
    __shared__ float xs[6400];
    __shared__ float hs[4096];
    __shared__ float scl[64];
    const int b = blockIdx.x;
    const int t = threadIdx.x;

    for (int idx = t; idx < 6400; idx += 256) xs[idx] = 0.f;
    __syncthreads();
    #pragma unroll
    for (int k = 0; k < 4; ++k) {
        int idx4 = t + k * 256;
        float4 v = *(const float4*)&x[(size_t)b * 4096 + idx4 * 4];
        int e0 = idx4 * 4;
        int c  = e0 >> 6;
        int hw = e0 & 63;
        int r = hw >> 3, cc = hw & 7;
        float* xp = &xs[c * 100 + (r + 1) * 10 + (cc + 1)];
        xp[0] = v.x; xp[1] = v.y; xp[2] = v.z; xp[3] = v.w;
    }
    __syncthreads();

    const int oc = t >> 2;
    const int hg = t & 3;
    float acc[16];
    #pragma unroll
    for (int k = 0; k < 16; ++k) acc[k] = 0.f;

    const float* wp = Wb + (size_t)oc * 64 * 9;
    for (int ic = 0; ic < 64; ++ic) {
        float w[9];
        #pragma unroll
        for (int j = 0; j < 9; ++j) w[j] = wp[ic * 9 + j];
        const float* xr = &xs[ic * 100];
        #pragma unroll
        for (int k = 0; k < 16; ++k) {
            int hw = hg * 16 + k;
            int r = hw >> 3, cc = hw & 7;
            int p0 = r * 10 + cc;
            float a = acc[k];
            a = fmaf(w[0], xr[p0],      a);
            a = fmaf(w[1], xr[p0 + 1],  a);
            a = fmaf(w[2], xr[p0 + 2],  a);
            a = fmaf(w[3], xr[p0 + 10], a);
            a = fmaf(w[4], xr[p0 + 11], a);
            a = fmaf(w[5], xr[p0 + 12], a);
            a = fmaf(w[6], xr[p0 + 20], a);
            a = fmaf(w[7], xr[p0 + 21], a);
            a = fmaf(w[8], xr[p0 + 22], a);
            acc[k] = a;
        }
    }
    float bias = bb[oc];
    #pragma unroll
    for (int k = 0; k < 16; ++k) {
        float v = acc[k] + bias;
        v = v > 0.f ? v : 0.f;
        hs[oc * 64 + hg * 16 + k] = v;
    }
    __syncthreads();
    if (t < 64) {
        float n2 = 0.f;
        for (int c = 0; c < 64; ++c) { float v = hs[c * 64 + t]; n2 = fmaf(v, v, n2); }
        scl[t] = (n2 / (1.f + n2)) * rsqrtf(n2 + 1e-8f);
    }
    __syncthreads();
    #pragma unroll
    for (int k = 0; k < 4; ++k) {
        int idx4 = t + k * 256;
        int e0 = idx4 * 4;
        int hw0 = e0 & 63;
        float4 o;
        o.x = hs[e0 + 0] * scl[hw0 + 0];
        o.y = hs[e0 + 1] * scl[hw0 + 1];
        o.z = hs[e0 + 2] * scl[hw0 + 2];
        o.w = hs[e0 + 3] * scl[hw0 + 3];
        *(float4*)&h[(size_t)b * 4096 + e0] = o;
    }
}

__global__ __launch_bounds__(1024) void caps_fused(
    const float* __restrict__ h0,
    const float* __restrict__ W1, const float* __restrict__ b1,
    const float* __restrict__ W2, const float* __restrict__ b2,
    const float* __restrict__ b_basic, const float* __restrict__ b_cls,
    float* __restrict__ out)
{
    __shared__ float HTa[4096];
    __shared__ float HTb[4096];
    __shared__ float BL[4096];
    __shared__ float CC[4096];

    const int b    = blockIdx.x;
    const int t    = threadIdx.x;
    const int wv   = t >> 6;      // wave 0..15
    const int lane = t & 63;
    const int Q    = lane & 15;
    const int G    = lane >> 4;

    // initial transposed load: HTa[i][c] = h0[b][c][i]
    {
        float4 v = *(const float4*)&h0[(size_t)b * 4096 + t * 4];
        int c  = t >> 4;
        int i0 = (t & 15) * 4;
        HTa[(i0 + 0) * 64 + c] = v.x;
        HTa[(i0 + 1) * 64 + c] = v.y;
        HTa[(i0 + 2) * 64 + c] = v.z;
        HTa[(i0 + 3) * 64 + c] = v.w;
    }

    // One cap layer; FIN is compile-time so the final layer (O=10, 1 o/wave)
    // has zero per-load guards.
    auto layer = [&](auto finc, const float* __restrict__ W,
                     const float* __restrict__ bias,
                     const float* __restrict__ bsrc,
                     float* HT, float* HTn) {
        constexpr bool FIN = decltype(finc)::value;
        constexpr int  O   = FIN ? 10 : 64;
        constexpr int  NOO = FIN ? 1 : 4;
        float* PP = HTn;   // [16][64] overlay; HTn rows 0..15 dead at softmax

        // prefetch logits into regs (hides under previous layer tail)
        float4 blv = make_float4(0.f, 0.f, 0.f, 0.f);
        if (FIN) {
            if (t < 160) blv = *(const float4*)&bsrc[t * 4];
        } else {
            blv = *(const float4*)&bsrc[t * 4];
        }
        // layer-invariant per-wave values
        float bb4[4];
        const float* WoS[4];
        const float* WoU[4];
        #pragma unroll
        for (int oo = 0; oo < NOO; ++oo) {
            int o = wv + 16 * oo;
            int om = (o < O) ? o : 0;        // idle waves (FIN): harmless row 0
            bb4[oo] = bias[om * 64 + lane];
            WoS[oo] = W + ((size_t)(om * 64 + lane) << 6);
            WoU[oo] = W + ((size_t)(om * 64 + G * 16) << 6) + 4 * Q;
        }
        __syncthreads();           // layer top: HT ready, old BL/CC dead
        if (!FIN || t < 160) *(float4*)&BL[t * 4] = blv;

        for (int it = 0; it < 3; ++it) {
            __syncthreads();   // A: BL current; HTn v-rows dead
            // -- softmax pass 1: exp + per-wave partial sums --
            float part = 0.f;
            #pragma unroll
            for (int r = 0; r < 4; ++r) {
                int o = 4 * wv + r;
                if (o < O) {
                    float e = expf(BL[o * 64 + lane]);
                    CC[o * 64 + lane] = e;
                    part += e;
                }
            }
            PP[wv * 64 + lane] = part;
            __syncthreads();   // B
            {
                float den = 0.f;
                #pragma unroll
                for (int w2 = 0; w2 < 16; ++w2) den += PP[w2 * 64 + lane];
                float rden = 1.f / den;
                #pragma unroll
                for (int r = 0; r < 4; ++r) {
                    int o = 4 * wv + r;
                    if (o < O) CC[o * 64 + lane] *= rden;
                }
            }
            __syncthreads();   // C: c complete; HT stable from here on

            if (wv < O) {
                // -- Y: y[o,c] = sum_i c[o,i] h[c,i] --
                float yy[4][4];
                float sc[4];
                #pragma unroll
                for (int a = 0; a < 4; ++a) {
                    sc[a] = 0.f;
                    #pragma unroll
                    for (int j2 = 0; j2 < 4; ++j2) yy[a][j2] = 0.f;
                }
                #pragma unroll
                for (int j = 0; j < 4; ++j) {
                    float4 h4[4];
                    #pragma unroll
                    for (int r = 0; r < 4; ++r)
                        h4[r] = *(float4*)&HT[(G * 16 + 4 * j + r) * 64 + 4 * Q];
                    #pragma unroll
                    for (int oo = 0; oo < NOO; ++oo) {
                        int o = wv + 16 * oo;
                        float4 c4 = *(const float4*)&CC[o * 64 + G * 16 + 4 * j];
                        yy[oo][0] = fmaf(c4.x, h4[0].x, yy[oo][0]);
                        yy[oo][1] = fmaf(c4.x, h4[0].y, yy[oo][1]);
                        yy[oo][2] = fmaf(c4.x, h4[0].z, yy[oo][2]);
                        yy[oo][3] = fmaf(c4.x, h4[0].w, yy[oo][3]);
                        yy[oo][0] = fmaf(c4.y, h4[1].x, yy[oo][0]);
                        yy[oo][1] = fmaf(c4.y, h4[1].y, yy[oo][1]);
                        yy[oo][2] = fmaf(c4.y, h4[1].z, yy[oo][2]);
                        yy[oo][3] = fmaf(c4.y, h4[1].w, yy[oo][3]);
                        yy[oo][0] = fmaf(c4.z, h4[2].x, yy[oo][0]);
                        yy[oo][1] = fmaf(c4.z, h4[2].y, yy[oo][1]);
                        yy[oo][2] = fmaf(c4.z, h4[2].z, yy[oo][2]);
                        yy[oo][3] = fmaf(c4.z, h4[2].w, yy[oo][3]);
                        yy[oo][0] = fmaf(c4.w, h4[3].x, yy[oo][0]);
                        yy[oo][1] = fmaf(c4.w, h4[3].y, yy[oo][1]);
                        yy[oo][2] = fmaf(c4.w, h4[3].z, yy[oo][2]);
                        yy[oo][3] = fmaf(c4.w, h4[3].w, yy[oo][3]);
                        sc[oo] += (c4.x + c4.y) + (c4.z + c4.w);
                    }
                }
                #pragma unroll
                for (int m = 16; m <= 32; m <<= 1) {
                    #pragma unroll
                    for (int oo = 0; oo < NOO; ++oo) {
                        yy[oo][0] += __shfl_xor(yy[oo][0], m, 64);
                        yy[oo][1] += __shfl_xor(yy[oo][1], m, 64);
                        yy[oo][2] += __shfl_xor(yy[oo][2], m, 64);
                        yy[oo][3] += __shfl_xor(yy[oo][3], m, 64);
                        sc[oo]    += __shfl_xor(sc[oo],    m, 64);
                    }
                }
                if (G == 0) {
                    #pragma unroll
                    for (int oo = 0; oo < NOO; ++oo) {
                        int o = wv + 16 * oo;
                        float4 w4;
                        w4.x = yy[oo][0]; w4.y = yy[oo][1];
                        w4.z = yy[oo][2]; w4.w = yy[oo][3];
                        *(float4*)&CC[o * 64 + 4 * Q] = w4;   // y row
                    }
                }

                // -- S: s[o,lane] = W_o[lane,:].y[o,:] ; k-outer, o-inner --
                float p[4][4];
                #pragma unroll
                for (int oo = 0; oo < NOO; ++oo) {
                    p[oo][0] = 0.f; p[oo][1] = 0.f; p[oo][2] = 0.f; p[oo][3] = 0.f;
                }
                #pragma unroll 4
                for (int k = 0; k < 16; ++k) {
                    #pragma unroll
                    for (int oo = 0; oo < NOO; ++oo) {
                        int o = wv + 16 * oo;
                        float4 w4 = *(const float4*)&WoS[oo][4 * k];
                        float4 y4 = *(const float4*)&CC[o * 64 + 4 * k];
                        p[oo][0] = fmaf(w4.x, y4.x, p[oo][0]);
                        p[oo][1] = fmaf(w4.y, y4.y, p[oo][1]);
                        p[oo][2] = fmaf(w4.z, y4.z, p[oo][2]);
                        p[oo][3] = fmaf(w4.w, y4.w, p[oo][3]);
                    }
                }
                float s4[4], n2[4], sb[4], vd4[4];
                #pragma unroll
                for (int oo = 0; oo < NOO; ++oo) {
                    float s = (p[oo][0] + p[oo][1]) + (p[oo][2] + p[oo][3]);
                    s = fmaf(bb4[oo], sc[oo], s);
                    s4[oo] = s;
                    n2[oo] = s * s;
                    sb[oo] = s * bb4[oo];
                }
                // fused butterfly: n2 (squash) + s.bias (for db) together
                #pragma unroll
                for (int m = 1; m < 64; m <<= 1) {
                    #pragma unroll
                    for (int oo = 0; oo < NOO; ++oo) {
                        n2[oo] += __shfl_xor(n2[oo], m, 64);
                        sb[oo] += __shfl_xor(sb[oo], m, 64);
                    }
                }
                #pragma unroll
                for (int oo = 0; oo < NOO; ++oo) {
                    int o = wv + 16 * oo;
                    float scale = (n2[oo] / (1.f + n2[oo])) * rsqrtf(n2[oo] + 1e-8f);
                    float v = s4[oo] * scale;
                    vd4[oo] = sb[oo] * scale;        // = v . bias_o
                    HTn[o * 64 + lane] = v;          // v row = next HT
                    if (FIN && it == 2) out[((size_t)b * 10 + o) * 64 + lane] = v;
                }

                if (it < 2) {
                    // -- U: u[o,c] = sum_d v[o,d] W[od,c] ; k-outer, o-inner --
                    float u[4][4];
                    #pragma unroll
                    for (int oo = 0; oo < NOO; ++oo) {
                        u[oo][0] = 0.f; u[oo][1] = 0.f; u[oo][2] = 0.f; u[oo][3] = 0.f;
                    }
                    #pragma unroll 4
                    for (int k = 0; k < 16; ++k) {
                        #pragma unroll
                        for (int oo = 0; oo < NOO; ++oo) {
                            int o = wv + 16 * oo;
                            float4 w4 = *(const float4*)&WoU[oo][k << 6];
                            float vv = HTn[o * 64 + G * 16 + k];
                            u[oo][0] = fmaf(vv, w4.x, u[oo][0]);
                            u[oo][1] = fmaf(vv, w4.y, u[oo][1]);
                            u[oo][2] = fmaf(vv, w4.z, u[oo][2]);
                            u[oo][3] = fmaf(vv, w4.w, u[oo][3]);
                        }
                    }
                    #pragma unroll
                    for (int m = 16; m <= 32; m <<= 1) {
                        #pragma unroll
                        for (int oo = 0; oo < NOO; ++oo) {
                            u[oo][0] += __shfl_xor(u[oo][0], m, 64);
                            u[oo][1] += __shfl_xor(u[oo][1], m, 64);
                            u[oo][2] += __shfl_xor(u[oo][2], m, 64);
                            u[oo][3] += __shfl_xor(u[oo][3], m, 64);
                        }
                    }
                    if (G == 0) {
                        #pragma unroll
                        for (int oo = 0; oo < NOO; ++oo) {
                            int o = wv + 16 * oo;
                            float4 uu;
                            uu.x = u[oo][0]; uu.y = u[oo][1];
                            uu.z = u[oo][2]; uu.w = u[oo][3];
                            *(float4*)&CC[o * 64 + 4 * Q] = uu;   // u row
                        }
                    }
                    // -- DB: db[o,i=lane] = sum_c u[o,c] h[c,i] --
                    float a4[4] = {0.f, 0.f, 0.f, 0.f};
                    #pragma unroll 4
                    for (int k = 0; k < 16; ++k) {
                        int cq = k ^ Q;
                        float4 hh = *(float4*)&HT[lane * 64 + 4 * cq];  // o-invariant
                        #pragma unroll
                        for (int oo = 0; oo < NOO; ++oo) {
                            int o = wv + 16 * oo;
                            float4 uu = *(float4*)&CC[o * 64 + 4 * cq];
                            a4[oo] = fmaf(uu.x, hh.x, a4[oo]);
                            a4[oo] = fmaf(uu.y, hh.y, a4[oo]);
                            a4[oo] = fmaf(uu.z, hh.z, a4[oo]);
                            a4[oo] = fmaf(uu.w, hh.w, a4[oo]);
                        }
                    }
                    #pragma unroll
                    for (int oo = 0; oo < NOO; ++oo) {
                        int o = wv + 16 * oo;
                        BL[o * 64 + lane] += a4[oo] + vd4[oo];
                    }
                }
            }
        }
    };

    layer(std::integral_constant<bool, false>{}, W1, b1,
          b_basic + (((size_t)0 * 128 + b) << 12), HTa, HTb);
    layer(std::integral_constant<bool, false>{}, W1, b1,
          b_basic + (((size_t)1 * 128 + b) << 12), HTb, HTa);
    layer(std::integral_constant<bool, false>{}, W1, b1,
          b_basic + (((size_t)2 * 128 + b) << 12), HTa, HTb);
    layer(std::integral_constant<bool, true>{}, W2, b2,
          b_cls + (size_t)b * 640, HTb, HTa);
}

extern "C" void kernel_launch(void* const* d_in, const int* in_sizes, int n_in,
                              void* d_out, int out_size, void* d_ws, size_t ws_size,
                              hipStream_t stream) {
    const float* x       = (const float*)d_in[0];
    const float* Wb      = (const float*)d_in[1];
    const float* bb      = (const float*)d_in[2];
    const float* W1      = (const float*)d_in[3];
    const float* b1      = (const float*)d_in[4];
    const float* W2      = (const float*)d_in[5];
    const float* b2      = (const float*)d_in[6];
    const float* b_basic = (const float*)d_in[7];
    const float* b_cls   = (const float*)d_in[8];
    float* out = (float*)d_out;

    float* h0 = (float*)d_ws;   // [128,64,64]

    conv_squash_kernel<<<128, 256, 0, stream>>>(x, Wb, bb, h0);
    caps_fused<<<128, 1024, 0, stream>>>(h0, W1, b1, W2, b2, b_basic, b_cls, out);
}